// Round 1
// baseline (47.789 us; speedup 1.0000x reference)
//
#include <hip/hip_runtime.h>
#include <math.h>

// Problem constants
#define TT   16384
#define ADIM 1024

// fast tanh: 1 - 2/(e^{2x}+1); saturates correctly for |x| large
__device__ __forceinline__ float ftanh(float x) {
    float e2 = __expf(2.0f * x);
    return 1.0f - 2.0f * __builtin_amdgcn_rcpf(e2 + 1.0f);
}

// K1: dec_proj partials. grid=64 blocks, 256 thr. block b handles d in [16b,16b+16)
__global__ void k1_gemv_part(const float* __restrict__ dec_z, const float* __restrict__ W,
                             float* __restrict__ dp_part) {
    int b = blockIdx.x, tid = threadIdx.x;
    float4 acc = {0.f, 0.f, 0.f, 0.f};
#pragma unroll
    for (int i = 0; i < 16; ++i) {
        int d = b * 16 + i;
        float z = dec_z[d];
        float4 wr = reinterpret_cast<const float4*>(W + (size_t)d * ADIM)[tid];
        acc.x += wr.x * z; acc.y += wr.y * z; acc.z += wr.z * z; acc.w += wr.w * z;
    }
    reinterpret_cast<float4*>(dp_part)[b * 256 + tid] = acc;
}

// K1b: reduce 64 partials + b_dec -> dp[1024]. grid=4 x 256 thr
__global__ void k1b_reduce(const float* __restrict__ dp_part, const float* __restrict__ b_dec,
                           float* __restrict__ dp) {
    int col = blockIdx.x * 256 + threadIdx.x;
    float s = b_dec[col];
    for (int b = 0; b < 64; ++b) s += dp_part[b * ADIM + col];
    dp[col] = s;
}

// K2: e_scaled[t] = 2*( sum_a tanh(pre[t,a]+dp[a])*wg[a] + bg + mask[t] )
// grid=TT blocks, 256 thr; each thread one float4 of the 1024-wide row
__global__ void k2_escore(const float* __restrict__ pre, const float* __restrict__ dp,
                          const float* __restrict__ wg, const float* __restrict__ bg,
                          const float* __restrict__ mask, float* __restrict__ e_out) {
    int t = blockIdx.x, tid = threadIdx.x;
    float4 p = reinterpret_cast<const float4*>(pre + (size_t)t * ADIM)[tid];
    float4 d = reinterpret_cast<const float4*>(dp)[tid];
    float4 g = reinterpret_cast<const float4*>(wg)[tid];
    float s = ftanh(p.x + d.x) * g.x + ftanh(p.y + d.y) * g.y +
              ftanh(p.z + d.z) * g.z + ftanh(p.w + d.w) * g.w;
#pragma unroll
    for (int off = 32; off > 0; off >>= 1) s += __shfl_xor(s, off, 64);
    __shared__ float red[4];
    int wv = tid >> 6;
    if ((tid & 63) == 0) red[wv] = s;
    __syncthreads();
    if (tid == 0) {
        float tot = red[0] + red[1] + red[2] + red[3] + bg[0] + mask[t];
        e_out[t] = 2.0f * tot;
    }
}

// K3: softmax over 16384, single block of 1024 threads, 16 elems/thread
__global__ void __launch_bounds__(1024) k3_softmax(const float* __restrict__ e,
                                                   float* __restrict__ w_out) {
    int tid = threadIdx.x;
    int lane = tid & 63, wv = tid >> 6;
    float v[16];
    float m = -1e30f;
#pragma unroll
    for (int i = 0; i < 16; ++i) { v[i] = e[tid + i * 1024]; m = fmaxf(m, v[i]); }
#pragma unroll
    for (int off = 32; off > 0; off >>= 1) m = fmaxf(m, __shfl_xor(m, off, 64));
    __shared__ float sm[16];
    if (lane == 0) sm[wv] = m;
    __syncthreads();
    if (tid == 0) {
        float mm = sm[0];
        for (int i = 1; i < 16; ++i) mm = fmaxf(mm, sm[i]);
        sm[0] = mm;
    }
    __syncthreads();
    m = sm[0];
    float s = 0.f;
#pragma unroll
    for (int i = 0; i < 16; ++i) { v[i] = __expf(v[i] - m); s += v[i]; }
#pragma unroll
    for (int off = 32; off > 0; off >>= 1) s += __shfl_xor(s, off, 64);
    __shared__ float ss[16];
    if (lane == 0) ss[wv] = s;
    __syncthreads();
    if (tid == 0) {
        float t = 0.f;
        for (int i = 0; i < 16; ++i) t += ss[i];
        ss[0] = t;
    }
    __syncthreads();
    float inv = 1.0f / ss[0];
#pragma unroll
    for (int i = 0; i < 16; ++i) w_out[tid + i * 1024] = v[i] * inv;
}

// K4: context partials. grid=256 chunks x 256 thr; chunk owns 64 t-rows, thread owns
// 4 consecutive cols (float4) of the 1024-wide row
__global__ void k4_ctx_part(const float* __restrict__ enc, const float* __restrict__ w,
                            float* __restrict__ c_part) {
    int chunk = blockIdx.x, tid = threadIdx.x;
    float4 acc = {0.f, 0.f, 0.f, 0.f};
    const float4* eh = reinterpret_cast<const float4*>(enc);
    for (int i = 0; i < 64; ++i) {
        int t = chunk * 64 + i;
        float wv = w[t];
        float4 v = eh[(size_t)t * 256 + tid];
        acc.x += v.x * wv; acc.y += v.y * wv; acc.z += v.z * wv; acc.w += v.w * wv;
    }
    reinterpret_cast<float4*>(c_part)[chunk * 256 + tid] = acc;
}

// K5: reduce 256 chunk-partials -> c[1024]. grid=4 x 256 thr
__global__ void k5_ctx_reduce(const float* __restrict__ c_part, float* __restrict__ c) {
    int col = blockIdx.x * 256 + threadIdx.x;
    float s = 0.f;
    for (int ch = 0; ch < 256; ++ch) s += c_part[ch * ADIM + col];
    c[col] = s;
}

extern "C" void kernel_launch(void* const* d_in, const int* in_sizes, int n_in,
                              void* d_out, int out_size, void* d_ws, size_t ws_size,
                              hipStream_t stream) {
    const float* dec_z = (const float*)d_in[0];
    // d_in[1] = att_prev (unused by reference math)
    const float* pre   = (const float*)d_in[2];
    const float* enc   = (const float*)d_in[3];
    const float* mask  = (const float*)d_in[4];
    const float* W_dec = (const float*)d_in[5];
    const float* b_dec = (const float*)d_in[6];
    const float* wg    = (const float*)d_in[7];
    const float* bg    = (const float*)d_in[8];

    float* out   = (float*)d_out;
    float* c_out = out;            // [1024]
    float* w_out = out + ADIM;     // [16384]

    char* ws = (char*)d_ws;
    float* dp_part = (float*)ws;                                   // 64*1024 f
    float* dp      = (float*)(ws + (size_t)64 * ADIM * 4);         // 1024 f
    float* e_sc    = (float*)(ws + (size_t)65 * ADIM * 4);         // 16384 f
    float* c_part  = (float*)(ws + ((size_t)65 * ADIM + TT) * 4);  // 256*1024 f

    k1_gemv_part<<<64, 256, 0, stream>>>(dec_z, W_dec, dp_part);
    k1b_reduce<<<4, 256, 0, stream>>>(dp_part, b_dec, dp);
    k2_escore<<<TT, 256, 0, stream>>>(pre, dp, wg, bg, mask, e_sc);
    k3_softmax<<<1, 1024, 0, stream>>>(e_sc, w_out);
    k4_ctx_part<<<256, 256, 0, stream>>>(enc, w_out, c_part);
    k5_ctx_reduce<<<4, 256, 0, stream>>>(c_part, c_out);
}

// Round 2
// 38.012 us; speedup vs baseline: 1.2572x; 1.2572x over previous
//
#include <hip/hip_runtime.h>
#include <math.h>

#define TT   16384
#define ADIM 1024
#define NCH  512     // chunks (blocks) in fused main kernel
#define RPW  8       // rows per wave: NCH * 4 waves * RPW = TT
#define NCH2 64      // second-level context chunks

// fast tanh: 1 - 2/(e^{2x}+1); saturates correctly for large |x|
__device__ __forceinline__ float ftanh(float x) {
    float e2 = __expf(2.0f * x);
    return 1.0f - 2.0f * __builtin_amdgcn_rcpf(e2 + 1.0f);
}

// K1: dec GEMV partials. grid=256, block b handles rows [4b, 4b+4)
__global__ void k1_gemv_part(const float* __restrict__ z, const float* __restrict__ W,
                             float* __restrict__ part) {
    int b = blockIdx.x, tid = threadIdx.x;
    float4 acc = {0.f, 0.f, 0.f, 0.f};
#pragma unroll
    for (int i = 0; i < 4; ++i) {
        int d = b * 4 + i;
        float zv = z[d];
        float4 w4 = reinterpret_cast<const float4*>(W)[(size_t)d * 256 + tid];
        acc.x += zv * w4.x; acc.y += zv * w4.y; acc.z += zv * w4.z; acc.w += zv * w4.w;
    }
    reinterpret_cast<float4*>(part)[(size_t)b * 256 + tid] = acc;
}

// K2: reduce 256 partials -> dp[1024]. grid=64, block b covers cols [16b,16b+16)
__global__ void k2_gemv_red(const float* __restrict__ part, const float* __restrict__ bdec,
                            float* __restrict__ dp) {
    int b = blockIdx.x, tid = threadIdx.x;
    int lane = tid & 63, wv = tid >> 6;
    int rsub = lane >> 2;   // 0..15 row-subgroup within wave
    int colg = lane & 3;    // float4 group within block's 16 cols
    float4 acc = {0.f, 0.f, 0.f, 0.f};
#pragma unroll
    for (int i = 0; i < 4; ++i) {
        int row = i * 64 + wv * 16 + rsub;
        float4 v = reinterpret_cast<const float4*>(part)[(size_t)row * 256 + b * 4 + colg];
        acc.x += v.x; acc.y += v.y; acc.z += v.z; acc.w += v.w;
    }
#pragma unroll
    for (int off = 4; off <= 32; off <<= 1) {
        acc.x += __shfl_xor(acc.x, off, 64);
        acc.y += __shfl_xor(acc.y, off, 64);
        acc.z += __shfl_xor(acc.z, off, 64);
        acc.w += __shfl_xor(acc.w, off, 64);
    }
    __shared__ float4 lds[4][4];
    if (lane < 4) lds[wv][lane] = acc;
    __syncthreads();
    if (tid < 4) {
        float4 t = {0.f, 0.f, 0.f, 0.f};
#pragma unroll
        for (int w = 0; w < 4; ++w) {
            float4 v = lds[w][tid];
            t.x += v.x; t.y += v.y; t.z += v.z; t.w += v.w;
        }
        float4 bd = reinterpret_cast<const float4*>(bdec)[b * 4 + tid];
        t.x += bd.x; t.y += bd.y; t.z += bd.z; t.w += bd.w;
        reinterpret_cast<float4*>(dp)[b * 4 + tid] = t;
    }
}

// K3: fused e-score + online-softmax context partials.
// grid=NCH blocks x 256 thr. Block b rows [32b, 32b+32), wave wv rows t0..t0+RPW.
// Per wave: running (m, s, cacc[1024]); block-combines 4 waves -> cpart[b], m/s[b]; e to ws.
__global__ void __launch_bounds__(256) k3_fused(
    const float* __restrict__ pre, const float* __restrict__ enc,
    const float* __restrict__ dp, const float* __restrict__ wg,
    const float* __restrict__ bgp, const float* __restrict__ mask,
    float* __restrict__ e_out, float* __restrict__ m_out,
    float* __restrict__ s_out, float* __restrict__ cpart) {
    int b = blockIdx.x, tid = threadIdx.x;
    int lane = tid & 63, wv = tid >> 6;
    float4 d4[4], g4[4];
    const float4* dp4 = reinterpret_cast<const float4*>(dp);
    const float4* wg4 = reinterpret_cast<const float4*>(wg);
#pragma unroll
    for (int j = 0; j < 4; ++j) { d4[j] = dp4[j * 64 + lane]; g4[j] = wg4[j * 64 + lane]; }
    float bgv = bgp[0];
    float m = -3.0e38f, s = 0.f;
    float4 ca[4] = {{0,0,0,0},{0,0,0,0},{0,0,0,0},{0,0,0,0}};
    int t0 = b * (4 * RPW) + wv * RPW;
    for (int i = 0; i < RPW; ++i) {
        int t = t0 + i;
        const float4* pr = reinterpret_cast<const float4*>(pre) + (size_t)t * 256;
        const float4* er = reinterpret_cast<const float4*>(enc) + (size_t)t * 256;
        float4 p[4], ev[4];
#pragma unroll
        for (int j = 0; j < 4; ++j) { p[j] = pr[j * 64 + lane]; ev[j] = er[j * 64 + lane]; }
        float dot = 0.f;
#pragma unroll
        for (int j = 0; j < 4; ++j) {
            dot += ftanh(p[j].x + d4[j].x) * g4[j].x;
            dot += ftanh(p[j].y + d4[j].y) * g4[j].y;
            dot += ftanh(p[j].z + d4[j].z) * g4[j].z;
            dot += ftanh(p[j].w + d4[j].w) * g4[j].w;
        }
#pragma unroll
        for (int off = 32; off; off >>= 1) dot += __shfl_xor(dot, off, 64);
        float et = 2.0f * (dot + bgv + mask[t]);
        if (lane == 0) e_out[t] = et;
        float mn = fmaxf(m, et);
        float sc = __expf(m - mn);
        float pp = __expf(et - mn);
        s = s * sc + pp;
#pragma unroll
        for (int j = 0; j < 4; ++j) {
            ca[j].x = ca[j].x * sc + pp * ev[j].x;
            ca[j].y = ca[j].y * sc + pp * ev[j].y;
            ca[j].z = ca[j].z * sc + pp * ev[j].z;
            ca[j].w = ca[j].w * sc + pp * ev[j].w;
        }
        m = mn;
    }
    // block combine: 4 waves -> one chunk partial
    __shared__ float lm[4], ls[4];
    __shared__ float4 lc[4][256];
#pragma unroll
    for (int j = 0; j < 4; ++j) lc[wv][j * 64 + lane] = ca[j];
    if (lane == 0) { lm[wv] = m; ls[wv] = s; }
    __syncthreads();
    float Mb = fmaxf(fmaxf(lm[0], lm[1]), fmaxf(lm[2], lm[3]));
    float s0 = __expf(lm[0] - Mb), s1 = __expf(lm[1] - Mb);
    float s2 = __expf(lm[2] - Mb), s3 = __expf(lm[3] - Mb);
    if (tid == 0) {
        m_out[b] = Mb;
        s_out[b] = ls[0] * s0 + ls[1] * s1 + ls[2] * s2 + ls[3] * s3;
    }
    float4 v0 = lc[0][tid], v1 = lc[1][tid], v2 = lc[2][tid], v3 = lc[3][tid];
    float4 o;
    o.x = v0.x * s0 + v1.x * s1 + v2.x * s2 + v3.x * s3;
    o.y = v0.y * s0 + v1.y * s1 + v2.y * s2 + v3.y * s3;
    o.z = v0.z * s0 + v1.z * s1 + v2.z * s2 + v3.z * s3;
    o.w = v0.w * s0 + v1.w * s1 + v2.w * s2 + v3.w * s3;
    reinterpret_cast<float4*>(cpart)[(size_t)b * 256 + tid] = o;
}

// K4: global M,S + fold 512 chunk partials -> 64. grid=NCH2 blocks.
__global__ void __launch_bounds__(256) k4_fold(
    const float* __restrict__ m_arr, const float* __restrict__ s_arr,
    const float* __restrict__ cpart, float* __restrict__ cpart2,
    float* __restrict__ msout) {
    int b = blockIdx.x, tid = threadIdx.x;
    int lane = tid & 63, wv = tid >> 6;
    __shared__ float redm[4], reds[4];
    float mloc = fmaxf(m_arr[tid], m_arr[tid + 256]);
#pragma unroll
    for (int off = 32; off; off >>= 1) mloc = fmaxf(mloc, __shfl_xor(mloc, off, 64));
    if (lane == 0) redm[wv] = mloc;
    __syncthreads();
    float M = fmaxf(fmaxf(redm[0], redm[1]), fmaxf(redm[2], redm[3]));
    float4 acc = {0.f, 0.f, 0.f, 0.f};
#pragma unroll
    for (int i = 0; i < 8; ++i) {
        int r = b * 8 + i;
        float sc = __expf(m_arr[r] - M);
        float4 v = reinterpret_cast<const float4*>(cpart)[(size_t)r * 256 + tid];
        acc.x += sc * v.x; acc.y += sc * v.y; acc.z += sc * v.z; acc.w += sc * v.w;
    }
    reinterpret_cast<float4*>(cpart2)[(size_t)b * 256 + tid] = acc;
    if (b == 0) {
        float sl = s_arr[tid] * __expf(m_arr[tid] - M)
                 + s_arr[tid + 256] * __expf(m_arr[tid + 256] - M);
#pragma unroll
        for (int off = 32; off; off >>= 1) sl += __shfl_xor(sl, off, 64);
        if (lane == 0) reds[wv] = sl;
        __syncthreads();
        if (tid == 0) {
            float S = reds[0] + reds[1] + reds[2] + reds[3];
            msout[0] = M;
            msout[1] = 1.0f / S;
        }
    }
}

// K5: final. blocks 0..15: c columns; blocks 16..31: w = exp(e-M)*invS.
__global__ void __launch_bounds__(256) k5_final(
    const float* __restrict__ cpart2, const float* __restrict__ e,
    const float* __restrict__ ms, float* __restrict__ c_out,
    float* __restrict__ w_out) {
    int b = blockIdx.x, tid = threadIdx.x;
    float M = ms[0], invS = ms[1];
    if (b < 16) {
        int rs = tid >> 4;   // 0..15
        int cg = tid & 15;   // 0..15 float4 group within block's 64 cols
        float4 acc = {0.f, 0.f, 0.f, 0.f};
#pragma unroll
        for (int i = 0; i < 4; ++i) {
            int r = rs * 4 + i;
            float4 v = reinterpret_cast<const float4*>(cpart2)[(size_t)r * 256 + b * 16 + cg];
            acc.x += v.x; acc.y += v.y; acc.z += v.z; acc.w += v.w;
        }
        __shared__ float4 lds[16][16];
        lds[rs][cg] = acc;
        __syncthreads();
        if (tid < 16) {
            float4 t = {0.f, 0.f, 0.f, 0.f};
#pragma unroll
            for (int r = 0; r < 16; ++r) {
                float4 v = lds[r][tid];
                t.x += v.x; t.y += v.y; t.z += v.z; t.w += v.w;
            }
            t.x *= invS; t.y *= invS; t.z *= invS; t.w *= invS;
            reinterpret_cast<float4*>(c_out)[b * 16 + tid] = t;
        }
    } else {
        int base = (b - 16) * 256 + tid;
        float4 ev = reinterpret_cast<const float4*>(e)[base];
        float4 w;
        w.x = __expf(ev.x - M) * invS;
        w.y = __expf(ev.y - M) * invS;
        w.z = __expf(ev.z - M) * invS;
        w.w = __expf(ev.w - M) * invS;
        reinterpret_cast<float4*>(w_out)[base] = w;
    }
}

extern "C" void kernel_launch(void* const* d_in, const int* in_sizes, int n_in,
                              void* d_out, int out_size, void* d_ws, size_t ws_size,
                              hipStream_t stream) {
    const float* dec_z = (const float*)d_in[0];
    // d_in[1] = att_prev (unused)
    const float* pre   = (const float*)d_in[2];
    const float* enc   = (const float*)d_in[3];
    const float* mask  = (const float*)d_in[4];
    const float* W_dec = (const float*)d_in[5];
    const float* b_dec = (const float*)d_in[6];
    const float* wg    = (const float*)d_in[7];
    const float* bg    = (const float*)d_in[8];

    float* out   = (float*)d_out;
    float* c_out = out;            // [1024]
    float* w_out = out + ADIM;     // [16384]

    float* ws = (float*)d_ws;
    float* part   = ws;                       // 256*1024
    float* dp     = part + 256 * ADIM;        // 1024
    float* e_sc   = dp + ADIM;                // 16384
    float* m_arr  = e_sc + TT;                // 512
    float* s_arr  = m_arr + NCH;              // 512
    float* cpart  = s_arr + NCH;              // 512*1024
    float* cpart2 = cpart + (size_t)NCH * ADIM;   // 64*1024
    float* ms     = cpart2 + (size_t)NCH2 * ADIM; // 2

    k1_gemv_part<<<256, 256, 0, stream>>>(dec_z, W_dec, part);
    k2_gemv_red<<<64, 256, 0, stream>>>(part, b_dec, dp);
    k3_fused<<<NCH, 256, 0, stream>>>(pre, enc, dp, wg, bg, mask,
                                      e_sc, m_arr, s_arr, cpart);
    k4_fold<<<NCH2, 256, 0, stream>>>(m_arr, s_arr, cpart, cpart2, ms);
    k5_final<<<32, 256, 0, stream>>>(cpart2, e_sc, ms, c_out, w_out);
}